// Round 12
// baseline (432.605 us; speedup 1.0000x reference)
//
#include <hip/hip_runtime.h>
#include <cstdint>
#include <cstddef>

// x[B=512, L=32, H=32, D=128]; per (l,h): Linear(128->128) -> GELU -> Linear(128->128)
// R12: persistent (lh, half-batch) blocks; x loaded DIRECTLY to VGPRs (no LDS
// staging, no DMA-barrier coupling) pipelined one ks-batch ahead per wave;
// LDS only holds H ping-pong -> ONE barrier per tile; 12 waves/CU.
#define LH      1024
#define Dd      128
#define BT      64
#define NTILE   4             // tiles per block (half the batch)
#define XSTRIDE (LH * Dd)

typedef __attribute__((ext_vector_type(8))) short bf16x8;
typedef __attribute__((ext_vector_type(4))) float f32x4;

static __device__ __forceinline__ short f2bf(float f) {
  return __builtin_bit_cast(short, (__bf16)f);
}

// tanh-form GELU as one sigmoid; |diff| vs erf-gelu ~3e-3 << 0.185 threshold
static __device__ __forceinline__ float gelu_fast(float v) {
  float v2 = v * v;
  float u2 = v * (1.5957691216f + 0.0713548163f * v2);
  return v / (1.0f + __expf(-u2));
}

// LDS-only barrier: H writes drained; global loads/stores stay in flight.
#define BAR_LGKM() do {                                          \
  __builtin_amdgcn_sched_barrier(0);                             \
  asm volatile("s_waitcnt lgkmcnt(0)" ::: "memory");             \
  __builtin_amdgcn_s_barrier();                                  \
  __builtin_amdgcn_sched_barrier(0);                             \
} while (0)

__global__ __launch_bounds__(256, 3) void fused_mlp_direct(
    const float* __restrict__ x, const float* __restrict__ W1,
    const float* __restrict__ b1, const float* __restrict__ W2,
    const float* __restrict__ b2, float* __restrict__ out) {
  // LDS: ONLY the H ping-pong (bf16 [64][128] x2 = 32 KB), XOR-swizzled.
  // Safety of 1 barrier/tile: tile t writes Hs[t&1]; a wave reaching tile
  // t+2's writes of Hs[t&1] has passed tile t+1's barrier, which every wave
  // reaches only AFTER its tile-t GEMM2 reads (program order) -> no race.
  __shared__ alignas(16) short Hs[2][BT * Dd];

  const int tid  = threadIdx.x;
  const int lane = tid & 63;
  const int wid  = tid >> 6;     // 4 waves, each owns 32 N-columns
  const int lr   = lane & 15;
  const int lg   = lane >> 4;

  const int bid = blockIdx.x;
  // (lh, half): the two half-batch sharers of one lh are 8 bids apart ->
  // same XCD (bid%8 equal) and temporally adjacent -> W L2-shared.
  const int lh   = (bid & 7) * 128 + (bid >> 4);
  const int half = (bid >> 3) & 1;
  const int row0 = half * (NTILE * BT);
  const int n0   = wid * 32;

  const float* w1 = W1 + (size_t)lh * (Dd * Dd);
  const float* w2 = W2 + (size_t)lh * (Dd * Dd);
  // per-lane x base: row (row0+lr), col-block lh, k-offset lg*8
  const float* xa = x + ((size_t)(row0 + lr) * LH + lh) * Dd + lg * 8;
  float* oa = out + ((size_t)row0 * LH + lh) * Dd;

  // ---- issue tile0/ks0 x loads FIRST (critical path), then W gather ----
  float4 xf[4][2];
#pragma unroll
  for (int mt = 0; mt < 4; ++mt) {
    const float4* p = (const float4*)(xa + (size_t)(mt * 16) * XSTRIDE);
    xf[mt][0] = p[0];
    xf[mt][1] = p[1];
  }

  bf16x8 bw1[4][2], bw2[4][2];
#pragma unroll
  for (int ks = 0; ks < 4; ++ks)
#pragma unroll
    for (int nt = 0; nt < 2; ++nt) {
      const float* p1 = w1 + (size_t)(ks * 32 + lg * 8) * Dd + n0 + nt * 16 + lr;
      const float* p2 = w2 + (size_t)(ks * 32 + lg * 8) * Dd + n0 + nt * 16 + lr;
      bf16x8 a, b;
#pragma unroll
      for (int j = 0; j < 8; ++j) { a[j] = f2bf(p1[j * Dd]); b[j] = f2bf(p2[j * Dd]); }
      bw1[ks][nt] = a;
      bw2[ks][nt] = b;
    }

  const float bb1_0 = b1[lh * Dd + n0 + lr];
  const float bb1_1 = b1[lh * Dd + n0 + 16 + lr];
  const float bb2_0 = b2[lh * Dd + n0 + lr];
  const float bb2_1 = b2[lh * Dd + n0 + 16 + lr];

  for (int t = 0; t < NTILE; ++t) {
    const int c = t & 1;

    // ---------------- GEMM1: H = gelu(X @ W1 + b1) ----------------
    // x pipelined one ks-batch ahead, per-mt rolling issue (keeps only
    // ~8 extra load regs live; waits are per-wave vmcnt, no barriers).
    f32x4 acc[4][2];
#pragma unroll
    for (int mt = 0; mt < 4; ++mt) {
      acc[mt][0] = (f32x4){bb1_0, bb1_0, bb1_0, bb1_0};
      acc[mt][1] = (f32x4){bb1_1, bb1_1, bb1_1, bb1_1};
    }

#pragma unroll
    for (int ks = 0; ks < 4; ++ks) {
#pragma unroll
      for (int mt = 0; mt < 4; ++mt) {
        const float4 lo = xf[mt][0], hi = xf[mt][1];
        if (ks < 3) {          // next ks batch, same tile
          const float4* p = (const float4*)(xa + (size_t)(t * BT + mt * 16) * XSTRIDE + (ks + 1) * 32);
          xf[mt][0] = p[0];
          xf[mt][1] = p[1];
        } else if (t + 1 < NTILE) {   // ks0 of next tile: lands during GELU/BAR/GEMM2
          const float4* p = (const float4*)(xa + (size_t)((t + 1) * BT + mt * 16) * XSTRIDE);
          xf[mt][0] = p[0];
          xf[mt][1] = p[1];
        }
        bf16x8 a;
        a[0] = f2bf(lo.x); a[1] = f2bf(lo.y); a[2] = f2bf(lo.z); a[3] = f2bf(lo.w);
        a[4] = f2bf(hi.x); a[5] = f2bf(hi.y); a[6] = f2bf(hi.z); a[7] = f2bf(hi.w);
        acc[mt][0] = __builtin_amdgcn_mfma_f32_16x16x32_bf16(a, bw1[ks][0], acc[mt][0], 0, 0, 0);
        acc[mt][1] = __builtin_amdgcn_mfma_f32_16x16x32_bf16(a, bw1[ks][1], acc[mt][1], 0, 0, 0);
      }
    }

    // GELU in regs, write H[c] (XOR-swizzled), one barrier
    short hv[4][2][4];
#pragma unroll
    for (int mt = 0; mt < 4; ++mt)
#pragma unroll
      for (int nt = 0; nt < 2; ++nt)
#pragma unroll
        for (int r = 0; r < 4; ++r)
          hv[mt][nt][r] = f2bf(gelu_fast(acc[mt][nt][r]));

#pragma unroll
    for (int mt = 0; mt < 4; ++mt)
#pragma unroll
      for (int nt = 0; nt < 2; ++nt) {
        const int e = n0 + nt * 16 + lr;
#pragma unroll
        for (int r = 0; r < 4; ++r) {
          const int b = mt * 16 + lg * 4 + r;    // C/D row = (lane>>4)*4 + reg
          const int off = (b * 256 + e * 2) ^ ((b & 7) << 4);
          *(short*)((char*)Hs[c] + off) = hv[mt][nt][r];
        }
      }

    BAR_LGKM();   // H[c] visible; x loads/stores remain in flight

    // ---------------- GEMM2: out = H @ W2 + b2 (W2 in regs) ----------
    f32x4 acc2[4][2];
#pragma unroll
    for (int mt = 0; mt < 4; ++mt) {
      acc2[mt][0] = (f32x4){bb2_0, bb2_0, bb2_0, bb2_0};
      acc2[mt][1] = (f32x4){bb2_1, bb2_1, bb2_1, bb2_1};
    }
#pragma unroll
    for (int ks = 0; ks < 4; ++ks) {
      const int k2 = (ks * 32 + lg * 8) * 2;   // byte offset of 16B H granule
#pragma unroll
      for (int mt = 0; mt < 4; ++mt) {
        const int b = mt * 16 + lr;
        const int off = (b * 256 + k2) ^ ((b & 7) << 4);
        bf16x8 a = *(const bf16x8*)((const char*)Hs[c] + off);
#pragma unroll
        for (int nt = 0; nt < 2; ++nt)
          acc2[mt][nt] = __builtin_amdgcn_mfma_f32_16x16x32_bf16(a, bw2[ks][nt], acc2[mt][nt], 0, 0, 0);
      }
    }

    // stores: compiler-managed waits; they drain under the next tile's GEMM1
    {
      float* ob = oa + (size_t)(t * BT) * XSTRIDE;
#pragma unroll
      for (int mt = 0; mt < 4; ++mt)
#pragma unroll
        for (int nt = 0; nt < 2; ++nt) {
          const int e = n0 + nt * 16 + lr;
#pragma unroll
          for (int r = 0; r < 4; ++r) {
            const int b = mt * 16 + lg * 4 + r;
            ob[(size_t)b * XSTRIDE + e] = acc2[mt][nt][r];
          }
        }
    }
  }
}

extern "C" void kernel_launch(void* const* d_in, const int* in_sizes, int n_in,
                              void* d_out, int out_size, void* d_ws, size_t ws_size,
                              hipStream_t stream) {
  (void)in_sizes; (void)n_in; (void)d_ws; (void)ws_size; (void)out_size;
  const float* x  = (const float*)d_in[0];
  const float* W1 = (const float*)d_in[1];
  const float* b1 = (const float*)d_in[2];
  const float* W2 = (const float*)d_in[3];
  const float* b2 = (const float*)d_in[4];
  float* out = (float*)d_out;
  fused_mlp_direct<<<dim3(2048), dim3(256), 0, stream>>>(x, W1, b1, W2, b2, out);
}

// Round 13
// 306.708 us; speedup vs baseline: 1.4105x; 1.4105x over previous
//
#include <hip/hip_runtime.h>
#include <cstdint>
#include <cstddef>

// x[B=512, L=32, H=32, D=128]; per (l,h): Linear(128->128) -> GELU -> Linear(128->128)
// R13 = R11 (persistent-per-lh, DMA-staged x, W in regs, counted-vmcnt
// barriers) with BT 64->32: LDS 2x16KB=32KB -> 4-5 blocks/CU (was 2).
// R12 proved direct VGPR x-loads lose (latency exposure); R11 proved barrier
// drains are not the stall; remaining lever = independent blocks/CU.
#define LH      1024
#define Dd      128
#define BT      32            // batch rows per tile -> 16 KB f32 in LDS
#define NTILE   16            // 512 / 32
#define XSTRIDE (LH * Dd)

typedef __attribute__((ext_vector_type(8))) short bf16x8;
typedef __attribute__((ext_vector_type(4))) float f32x4;
typedef const __attribute__((address_space(1))) uint32_t gu32;
typedef __attribute__((address_space(3))) uint32_t lu32;

static __device__ __forceinline__ short f2bf(float f) {
  return __builtin_bit_cast(short, (__bf16)f);
}

// tanh-form GELU as one sigmoid; |diff| vs erf-gelu ~3e-3 << 0.185 threshold
static __device__ __forceinline__ float gelu_fast(float v) {
  float v2 = v * v;
  float u2 = v * (1.5957691216f + 0.0713548163f * v2);
  return v / (1.0f + __expf(-u2));
}

// LDS-only barrier: ds ops drained; global loads/stores stay in flight.
#define BAR_LGKM() do {                                          \
  __builtin_amdgcn_sched_barrier(0);                             \
  asm volatile("s_waitcnt lgkmcnt(0)" ::: "memory");             \
  __builtin_amdgcn_s_barrier();                                  \
  __builtin_amdgcn_sched_barrier(0);                             \
} while (0)

// End-of-iter barrier: vmcnt(16) retires everything except the newest 16
// vmem ops (= this tile's 16 output stores); in-order retire (m135) proves
// the 4 DMA issues for tile t+1 are complete. Stores drain under next GEMM1.
#define BAR_END() do {                                           \
  __builtin_amdgcn_sched_barrier(0);                             \
  asm volatile("s_waitcnt vmcnt(16) lgkmcnt(0)" ::: "memory");   \
  __builtin_amdgcn_s_barrier();                                  \
  __builtin_amdgcn_sched_barrier(0);                             \
} while (0)

__global__ __launch_bounds__(256, 4) void fused_mlp_persist(
    const float* __restrict__ x, const float* __restrict__ W1,
    const float* __restrict__ b1, const float* __restrict__ W2,
    const float* __restrict__ b2, float* __restrict__ out) {
  // 2 ping-pong buffers of 16 KB. Each: x f32 [32 rows][32 chunks of 16B],
  // chunk-index XOR-swizzled on the GLOBAL source addr (global_load_lds
  // writes LDS linearly, m104/m173). H bf16 [32][128] (8 KB) overlays bytes
  // 0..8K of the CURRENT buffer after GEMM1's reads are barrier-complete.
  __shared__ alignas(16) char smem[2][BT * Dd * 4];   // 32 KB total

  const int tid  = threadIdx.x;
  const int lane = tid & 63;
  const int wid  = tid >> 6;     // 4 waves, each owns 32 N-columns
  const int lr   = lane & 15;
  const int lg   = lane >> 4;

  const int lh = blockIdx.x;     // W reuse is intra-block
  const int n0 = wid * 32;

  const float* w1  = W1 + (size_t)lh * (Dd * Dd);
  const float* w2  = W2 + (size_t)lh * (Dd * Dd);
  const float* xlh = x   + (size_t)lh * Dd;
  float*       olh = out + (size_t)lh * Dd;

  // stage tile t into buffer buf: 4 DMA issues/wave, 16 KB/block in flight
  auto stage = [&](int t, int buf) {
#pragma unroll
    for (int i = 0; i < 4; ++i) {
      const int slot = wid * 4 + i;          // wave-uniform 1KB LDS slot
      const int row  = slot * 2 + (lane >> 5);
      const int cp   = lane & 31;            // chunk position in LDS
      const int c    = cp ^ (row & 15);      // global chunk (bijective swz)
      const float* g = xlh + (size_t)(t * BT + row) * XSTRIDE + c * 4;
      __builtin_amdgcn_global_load_lds((gu32*)g,
                                       (lu32*)(smem[buf] + slot * 1024),
                                       16, 0, 0);
    }
  };

  // ---- prologue: DMA tile 0; gather ALL W fragments to regs (once per
  // block, hidden under the DMA flight); biases.
  stage(0, 0);

  bf16x8 bw1[4][2], bw2[4][2];
#pragma unroll
  for (int ks = 0; ks < 4; ++ks)
#pragma unroll
    for (int nt = 0; nt < 2; ++nt) {
      const float* p1 = w1 + (size_t)(ks * 32 + lg * 8) * Dd + n0 + nt * 16 + lr;
      const float* p2 = w2 + (size_t)(ks * 32 + lg * 8) * Dd + n0 + nt * 16 + lr;
      bf16x8 a, b;
#pragma unroll
      for (int j = 0; j < 8; ++j) { a[j] = f2bf(p1[j * Dd]); b[j] = f2bf(p2[j * Dd]); }
      bw1[ks][nt] = a;
      bw2[ks][nt] = b;
    }

  const float bb1_0 = b1[lh * Dd + n0 + lr];
  const float bb1_1 = b1[lh * Dd + n0 + 16 + lr];
  const float bb2_0 = b2[lh * Dd + n0 + lr];
  const float bb2_1 = b2[lh * Dd + n0 + 16 + lr];

  // prologue barrier: full drain (DMA(0) + W loads), once per block
  __builtin_amdgcn_sched_barrier(0);
  asm volatile("s_waitcnt vmcnt(0) lgkmcnt(0)" ::: "memory");
  __builtin_amdgcn_s_barrier();
  __builtin_amdgcn_sched_barrier(0);

  for (int t = 0; t < NTILE; ++t) {
    const int cur = t & 1;

    // DMA(t+1) -> other buffer; that buffer proven free by BAR_END(t-1).
    if (t + 1 < NTILE) stage(t + 1, cur ^ 1);

    // ---------------- GEMM1: H = gelu(X @ W1 + b1) ----------------
    f32x4 acc[2][2];
#pragma unroll
    for (int mt = 0; mt < 2; ++mt) {
      acc[mt][0] = (f32x4){bb1_0, bb1_0, bb1_0, bb1_0};
      acc[mt][1] = (f32x4){bb1_1, bb1_1, bb1_1, bb1_1};
    }
#pragma unroll
    for (int ks = 0; ks < 4; ++ks) {
      bf16x8 af[2];
#pragma unroll
      for (int mt = 0; mt < 2; ++mt) {
        const int row = mt * 16 + lr;
        const int c0  = ks * 8 + lg * 2;
        const int m   = row & 15;
        const float4 lo = *(const float4*)(smem[cur] + row * 512 + ((c0)     ^ m) * 16);
        const float4 hi = *(const float4*)(smem[cur] + row * 512 + ((c0 + 1) ^ m) * 16);
        bf16x8 a;
        a[0] = f2bf(lo.x); a[1] = f2bf(lo.y); a[2] = f2bf(lo.z); a[3] = f2bf(lo.w);
        a[4] = f2bf(hi.x); a[5] = f2bf(hi.y); a[6] = f2bf(hi.z); a[7] = f2bf(hi.w);
        af[mt] = a;
      }
#pragma unroll
      for (int mt = 0; mt < 2; ++mt)
#pragma unroll
        for (int nt = 0; nt < 2; ++nt)
          acc[mt][nt] = __builtin_amdgcn_mfma_f32_16x16x32_bf16(af[mt], bw1[ks][nt], acc[mt][nt], 0, 0, 0);
    }

    // GELU in regs before the barrier
    short hv[2][2][4];
#pragma unroll
    for (int mt = 0; mt < 2; ++mt)
#pragma unroll
      for (int nt = 0; nt < 2; ++nt)
#pragma unroll
        for (int r = 0; r < 4; ++r)
          hv[mt][nt][r] = f2bf(gelu_fast(acc[mt][nt][r]));

    BAR_LGKM();   // all waves done reading x[cur]; stores/DMA stay in flight

#pragma unroll
    for (int mt = 0; mt < 2; ++mt)
#pragma unroll
      for (int nt = 0; nt < 2; ++nt) {
        const int e = n0 + nt * 16 + lr;
#pragma unroll
        for (int r = 0; r < 4; ++r) {
          const int b = mt * 16 + lg * 4 + r;   // C/D row = (lane>>4)*4 + reg
          const int off = (b * 256 + e * 2) ^ ((b & 7) << 4);
          *(short*)(smem[cur] + off) = hv[mt][nt][r];
        }
      }

    BAR_LGKM();   // H visible; stores/DMA still in flight

    // ---------------- GEMM2: out = H @ W2 + b2 (W2 in regs) ----------
    f32x4 acc2[2][2];
#pragma unroll
    for (int mt = 0; mt < 2; ++mt) {
      acc2[mt][0] = (f32x4){bb2_0, bb2_0, bb2_0, bb2_0};
      acc2[mt][1] = (f32x4){bb2_1, bb2_1, bb2_1, bb2_1};
    }
#pragma unroll
    for (int ks = 0; ks < 4; ++ks) {
      const int k2 = (ks * 32 + lg * 8) * 2;   // byte offset of 16B H granule
#pragma unroll
      for (int mt = 0; mt < 2; ++mt) {
        const int b = mt * 16 + lr;
        const int off = (b * 256 + k2) ^ ((b & 7) << 4);
        bf16x8 a = *(const bf16x8*)(smem[cur] + off);
#pragma unroll
        for (int nt = 0; nt < 2; ++nt)
          acc2[mt][nt] = __builtin_amdgcn_mfma_f32_16x16x32_bf16(a, bw2[ks][nt], acc2[mt][nt], 0, 0, 0);
      }
    }

    // epilogue: 16 f32 stores (64B contiguous per 16-lane group)
    {
      float* ob = olh + (size_t)(t * BT) * XSTRIDE;
#pragma unroll
      for (int mt = 0; mt < 2; ++mt)
#pragma unroll
        for (int nt = 0; nt < 2; ++nt) {
          const int e = n0 + nt * 16 + lr;
#pragma unroll
          for (int r = 0; r < 4; ++r) {
            const int b = mt * 16 + lg * 4 + r;
            ob[(size_t)b * XSTRIDE + e] = acc2[mt][nt][r];
          }
        }
    }

    // end-of-iter: prove DMA(t+1) landed; keep this tile's 16 stores in flight
    if (t + 1 < NTILE) BAR_END();
  }
}

extern "C" void kernel_launch(void* const* d_in, const int* in_sizes, int n_in,
                              void* d_out, int out_size, void* d_ws, size_t ws_size,
                              hipStream_t stream) {
  (void)in_sizes; (void)n_in; (void)d_ws; (void)ws_size; (void)out_size;
  const float* x  = (const float*)d_in[0];
  const float* W1 = (const float*)d_in[1];
  const float* b1 = (const float*)d_in[2];
  const float* W2 = (const float*)d_in[3];
  const float* b2 = (const float*)d_in[4];
  float* out = (float*)d_out;
  fused_mlp_persist<<<dim3(LH), dim3(256), 0, stream>>>(x, W1, b1, W2, b2, out);
}